// Round 6
// baseline (414.026 us; speedup 1.0000x reference)
//
#include <hip/hip_runtime.h>
#include <cstdint>
#include <cstddef>

// ---------------------------------------------------------------------------
// CausalSelfAttention: y = proj(softmax_causal(QK^T/sqrt(HD)) V), QKV = x@W_attn+b
// B=2 T=2048 C=2048 H=16 HD=128. All I/O fp32; internal compute bf16 MFMA.
// ---------------------------------------------------------------------------

typedef __bf16 bf16x8 __attribute__((ext_vector_type(8)));
typedef float  f32x4  __attribute__((ext_vector_type(4)));
typedef unsigned short u16x4 __attribute__((ext_vector_type(4)));
typedef unsigned short u16x8 __attribute__((ext_vector_type(8)));

__device__ __forceinline__ unsigned short f2bf(float f) {
  unsigned int u = __builtin_bit_cast(unsigned int, f);
  u += 0x7fffu + ((u >> 16) & 1u);       // round-to-nearest-even
  return (unsigned short)(u >> 16);
}

__device__ __forceinline__ void gld16(void* lds, const void* g) {
  // async global->LDS, 16B per lane; LDS dest is wave-uniform base + lane*16
  __builtin_amdgcn_global_load_lds(
      (const __attribute__((address_space(1))) void*)g,
      (__attribute__((address_space(3))) void*)lds, 16, 0, 0);
}

// ---------------------------------------------------------------------------
// fp32 -> bf16 elementwise (x conversion)
// ---------------------------------------------------------------------------
__global__ void cvt_f32_bf16_k(const float* __restrict__ in,
                               unsigned short* __restrict__ out, int n4) {
  int i = blockIdx.x * blockDim.x + threadIdx.x;
  int stride = gridDim.x * blockDim.x;
  for (; i < n4; i += stride) {
    float4 v = ((const float4*)in)[i];
    ushort4 o;
    o.x = f2bf(v.x); o.y = f2bf(v.y); o.z = f2bf(v.z); o.w = f2bf(v.w);
    ((ushort4*)out)[i] = o;
  }
}

// ---------------------------------------------------------------------------
// fp32 (R,C) -> bf16 transposed (C,R). 64x64 tile, float4 reads, 16B writes.
// LDS tile padded 64x65: both phases land at <=2 lanes/bank (free).
// ---------------------------------------------------------------------------
__global__ __launch_bounds__(256) void transpose_f32_bf16(
    const float* __restrict__ in, unsigned short* __restrict__ out,
    int R, int C) {
  __shared__ float tile[64][65];
  int c0 = blockIdx.x * 64, r0 = blockIdx.y * 64;
  int t = threadIdx.x;
  int lr = t >> 4, lc = (t & 15) * 4;
#pragma unroll
  for (int i = 0; i < 4; i++) {
    int row = lr + i * 16;
    float4 v = *(const float4*)&in[(size_t)(r0 + row) * C + c0 + lc];
    tile[row][lc] = v.x; tile[row][lc + 1] = v.y;
    tile[row][lc + 2] = v.z; tile[row][lc + 3] = v.w;
  }
  __syncthreads();
  int wr = t >> 3, wc = (t & 7) * 8;
#pragma unroll
  for (int i = 0; i < 2; i++) {
    int crow = wr + i * 32;
    u16x8 o;
#pragma unroll
    for (int j = 0; j < 8; j++) o[j] = f2bf(tile[wc + j][crow]);
    *(u16x8*)&out[(size_t)(c0 + crow) * R + r0 + wc] = o;
  }
}

// ---------------------------------------------------------------------------
// extract V^T (B,H,HD,T) bf16 from qkv (B*T, 3C) bf16. 64t x 64d tile.
// 16B global loads/stores; LDS u32-packs t and t+32 per slot.
// ---------------------------------------------------------------------------
__global__ __launch_bounds__(256) void extract_vT_k(
    const unsigned short* __restrict__ qkv, unsigned short* __restrict__ vT) {
  __shared__ unsigned int tile32[64][33];   // [d][t&31] packs (t, t+32)
  int bh = blockIdx.z, b = bh >> 4, h = bh & 15;
  int t0 = blockIdx.x * 64, d0 = blockIdx.y * 64;
  int t = threadIdx.x;
  int lr = t >> 3, lc = (t & 7) * 8;
  const unsigned short* src = qkv + (size_t)(b * 2048) * 6144 + 4096 + h * 128;
#pragma unroll
  for (int i = 0; i < 2; i++) {
    int row = lr + i * 32;
    u16x8 v = *(const u16x8*)&src[(size_t)(t0 + row) * 6144 + d0 + lc];
#pragma unroll
    for (int j = 0; j < 8; j++) {
      unsigned short* p = (unsigned short*)&tile32[lc + j][row & 31];
      p[row >> 5] = v[j];
    }
  }
  __syncthreads();
  int dr = t >> 2, tc = (t & 3) * 8;
  u16x8 lo, hi;
#pragma unroll
  for (int j = 0; j < 8; j++) {
    unsigned int u = tile32[dr][tc + j];
    lo[j] = (unsigned short)(u & 0xffffu);
    hi[j] = (unsigned short)(u >> 16);
  }
  unsigned short* dst = vT + (size_t)bh * 128 * 2048 + (size_t)(d0 + dr) * 2048 + t0;
  *(u16x8*)&dst[tc] = lo;
  *(u16x8*)&dst[tc + 32] = hi;
}

// ---------------------------------------------------------------------------
// m97-style GEMM (BK=32, the measured-best config): C = A * BT^T + bias.
// 128x128 tile, 4 waves (2x2 of 64x64), global_load_lds width-16, LDS XOR
// swizzle f(row)=(row>>1)&3 -> fragment ds_read_b128 conflict-free.
// Linear grid with XCD-aware swizzle: xcd=id&7 owns bn in
// [xcd*BN_PER_XCD, ...) so each XCD's L2 holds its B-tiles (512 KB each)
// while A streams through L3 -> staging loads L2-hit -> shorter pre-barrier
// vmcnt drain. M is fixed at 32 m-tiles (M=4096).
// ---------------------------------------------------------------------------
template <int OUT_BF16, int BN_PER_XCD>
__global__ __launch_bounds__(256) void gemm_bt(
    const unsigned short* __restrict__ A, const unsigned short* __restrict__ BT,
    const float* __restrict__ bias, void* __restrict__ Cout,
    int M, int N, int K) {
  __shared__ __align__(16) unsigned short sA[128 * 32];
  __shared__ __align__(16) unsigned short sB[128 * 32];

  const int tid = threadIdx.x, w = tid >> 6, lane = tid & 63;
  const int quad = lane >> 4, l16 = lane & 15;

  // XCD-aware block swizzle (id%8 -> XCD heuristic; perf-only)
  const int id = blockIdx.x;
  const int xcd = id & 7, j = id >> 3;
  const int bn = xcd * BN_PER_XCD + (j >> 5);
  const int bm = j & 31;
  const int m0 = bm * 128, n0 = bn * 128;
  const int wr = w >> 1, wc = w & 1;

  // staging: 512 chunks of 16B per tile; wave w owns chunks [w*128, w*128+128)
  // LDS slot s holds global chunk (row=s>>2, col=(s&3)^((s>>3)&3))
  const int c0 = w * 128 + lane;        // i=0 chunk
  const int c1 = w * 128 + 64 + lane;   // i=1 chunk
  const int sc0 = ((c0 & 3) ^ ((c0 >> 3) & 3));
  const int sc1 = ((c1 & 3) ^ ((c1 >> 3) & 3));
  const unsigned short* gA0 = A + (size_t)(m0 + (c0 >> 2)) * K + sc0 * 8;
  const unsigned short* gA1 = A + (size_t)(m0 + (c1 >> 2)) * K + sc1 * 8;
  const unsigned short* gB0 = BT + (size_t)(n0 + (c0 >> 2)) * K + sc0 * 8;
  const unsigned short* gB1 = BT + (size_t)(n0 + (c1 >> 2)) * K + sc1 * 8;
  unsigned short* lA0 = sA + (size_t)(w * 128) * 8;
  unsigned short* lA1 = sA + (size_t)(w * 128 + 64) * 8;
  unsigned short* lB0 = sB + (size_t)(w * 128) * 8;
  unsigned short* lB1 = sB + (size_t)(w * 128 + 64) * 8;

  // fragment read chunk: slot with s>>2==row and swizzled col == quad
  const int rch = quad ^ ((l16 >> 1) & 3);

  f32x4 acc[4][4] = {};

  for (int k0 = 0; k0 < K; k0 += 32) {
    gld16(lA0, gA0); gld16(lA1, gA1);
    gld16(lB0, gB0); gld16(lB1, gB1);
    gA0 += 32; gA1 += 32; gB0 += 32; gB1 += 32;
    __syncthreads();

    bf16x8 af[4], bfr[4];
#pragma unroll
    for (int mi = 0; mi < 4; mi++)
      af[mi] = *(const bf16x8*)&sA[(wr * 64 + mi * 16 + l16) * 32 + rch * 8];
#pragma unroll
    for (int ni = 0; ni < 4; ni++)
      bfr[ni] = *(const bf16x8*)&sB[(wc * 64 + ni * 16 + l16) * 32 + rch * 8];
#pragma unroll
    for (int mi = 0; mi < 4; mi++)
#pragma unroll
      for (int ni = 0; ni < 4; ni++)
        acc[mi][ni] = __builtin_amdgcn_mfma_f32_16x16x32_bf16(
            af[mi], bfr[ni], acc[mi][ni], 0, 0, 0);
    __syncthreads();
  }

  // epilogue: C/D layout row = quad*4+reg, col = l16
#pragma unroll
  for (int mi = 0; mi < 4; mi++) {
    int row = m0 + wr * 64 + mi * 16 + quad * 4;
#pragma unroll
    for (int ni = 0; ni < 4; ni++) {
      int col = n0 + wc * 64 + ni * 16 + l16;
      float bv = bias[col];
#pragma unroll
      for (int r = 0; r < 4; r++) {
        float v = acc[mi][ni][r] + bv;
        if (OUT_BF16)
          ((unsigned short*)Cout)[(size_t)(row + r) * N + col] = f2bf(v);
        else
          ((float*)Cout)[(size_t)(row + r) * N + col] = v;
      }
    }
  }
}

// ---------------------------------------------------------------------------
// Flash attention (causal), S^T formulation. Grid 512 linear:
//   g = id&31 -> (b,h) group (XCD-local K/V), qp = id>>5 -> pair (qp, 31-qp).
// Wave w owns q-cols [w*16,w*16+16). S^T = K Q^T via MFMA with A=K-frag,
// B=Q-frag. Each lane holds 16 k-values of ONE q-col -> softmax in-lane +
// 2 cross-quad shuffles; m/l/alpha scalar. P^T packs r-consecutive k ->
// 4 ds_write_b64 into per-wave P[q][k] (16B-chunk XOR swizzle), read back
// as A-frag b128 for PV. Double-buffered K/V staging via global_load_lds.
// ---------------------------------------------------------------------------
__global__ __launch_bounds__(256) void flash_attn(
    const unsigned short* __restrict__ qkv, const unsigned short* __restrict__ vT,
    unsigned short* __restrict__ yout) {
  __shared__ __align__(16) unsigned short sK[2][64 * 128];    // [t_k][d], swizzle &15
  __shared__ __align__(16) unsigned short sVT[2][128 * 64];   // [d][t_k], swizzle &7
  __shared__ __align__(16) unsigned short sP[4 * 16 * 64];    // per-wave P[q][k], chunk swizzle &7

  const int tid = threadIdx.x, w = tid >> 6, lane = tid & 63;
  const int quad = lane >> 4, l16 = lane & 15;
  const int id = blockIdx.x;
  const int g = id & 31;           // (b,h) group -> XCD g%8
  const int qp = id >> 5;          // 0..15
  const int b = g >> 4, h = g & 15;
  const int T = 2048, CC = 6144, HD = 128;
  const float qscale = 0.12753257252f;  // (1/sqrt(128)) * log2(e)

  const unsigned short* gK = qkv + (size_t)(b * T) * CC + 2048 + h * HD;
  const unsigned short* gV = vT + (size_t)(b * 16 + h) * HD * T;
  unsigned short* pw = sP + w * 16 * 64;

  // swizzled staging source pointers (slot -> global chunk)
  const unsigned short* kSrc[4];
  const unsigned short* vSrc[4];
  unsigned short* kDst[4];
  unsigned short* vDst[4];
#pragma unroll
  for (int i = 0; i < 4; i++) {
    int c = w * 256 + i * 64 + lane;
    int kR = c >> 4, kC = (c & 15) ^ (kR & 15);
    int vR = c >> 3, vC = (c & 7) ^ (vR & 7);
    kSrc[i] = gK + (size_t)kR * CC + kC * 8;
    vSrc[i] = gV + (size_t)vR * T + vC * 8;
    kDst[i] = (unsigned short*)sK + (size_t)(w * 256 + i * 64) * 8;
    vDst[i] = (unsigned short*)sVT + (size_t)(w * 256 + i * 64) * 8;
  }
  const int KBUF = 64 * 128, VBUF = 128 * 64;

  const int qtA = qp, qtB = 31 - qp;
  int qt = qtA, kt = 0;

  // ---- per-segment state (scalar per lane; this lane's q-col = l16) ----
  bf16x8 qf[4];
  float m_old, l_sum;
  f32x4 o[8] = {};
  {
    const size_t qrow = (size_t)(b * T + qt * 64 + w * 16 + l16) * CC + h * HD;
#pragma unroll
    for (int kb = 0; kb < 4; kb++) {
      bf16x8 raw = *(const bf16x8*)&qkv[qrow + kb * 32 + quad * 8];
      bf16x8 sc;
#pragma unroll
      for (int j = 0; j < 8; j++) sc[j] = (__bf16)((float)raw[j] * qscale);
      qf[kb] = sc;
    }
  }
  m_old = -1e30f; l_sum = 0.f;

  // stage tile 0 into buffer 0
#pragma unroll
  for (int i = 0; i < 4; i++) {
    gld16(kDst[i], kSrc[i]);
    gld16(vDst[i], vSrc[i]);
  }

  const int total = qtA + qtB + 2;   // = 33
  for (int it = 0; it < total; ++it) {
    __syncthreads();                 // buf[it&1] staged; prev iter's LDS reads done
    const int cur = it & 1;
    const bool segEnd = (kt == qt);

    // prefetch next tile into the other buffer (overlaps with compute below)
    if (it + 1 < total) {
      const int nkt = segEnd ? 0 : kt + 1;
      const int nb_ = (it + 1) & 1;
      const size_t kOff = (size_t)nkt * 64 * CC;   // K rows advance
      const int vOff = nkt * 64;                   // V cols advance
#pragma unroll
      for (int i = 0; i < 4; i++) {
        gld16(kDst[i] + (size_t)nb_ * KBUF, kSrc[i] + kOff);
        gld16(vDst[i] + (size_t)nb_ * VBUF, vSrc[i] + vOff);
      }
    }

    const unsigned short* sKc = (const unsigned short*)sK + (size_t)cur * KBUF;
    const unsigned short* sVc = (const unsigned short*)sVT + (size_t)cur * VBUF;

    // S^T = K Q^T : 64k x 16q per wave. A = K-frag, B = Q-frag.
    // C/D: k_local = kb*16 + quad*4 + r, q-col = l16.
    f32x4 s4[4] = {};
#pragma unroll
    for (int dc = 0; dc < 4; dc++) {
#pragma unroll
      for (int kb = 0; kb < 4; kb++) {
        int rr = kb * 16 + l16;
        int cc = (dc * 4 + quad) ^ l16;      // rr & 15 == l16
        bf16x8 kf = *(const bf16x8*)&sKc[rr * 128 + cc * 8];
        s4[kb] = __builtin_amdgcn_mfma_f32_16x16x32_bf16(kf, qf[dc], s4[kb], 0, 0, 0);
      }
    }

    // causal mask (diagonal tile only): k_local > q_local
    float sv[4][4];
#pragma unroll
    for (int kb = 0; kb < 4; kb++)
#pragma unroll
      for (int r = 0; r < 4; r++) {
        float v = s4[kb][r];
        if (segEnd) {
          if (kb * 16 + quad * 4 + r > w * 16 + l16) v = -1e30f;
        }
        sv[kb][r] = v;
      }

    // online softmax: in-lane over 16 k-values + 2 cross-quad shuffles
    float mx = sv[0][0];
#pragma unroll
    for (int kb = 0; kb < 4; kb++)
#pragma unroll
      for (int r = 0; r < 4; r++) mx = fmaxf(mx, sv[kb][r]);
    mx = fmaxf(mx, __shfl_xor(mx, 16));
    mx = fmaxf(mx, __shfl_xor(mx, 32));
    float m_new = fmaxf(m_old, mx);
    float a = exp2f(m_old - m_new);
    float ssum = 0.f;
#pragma unroll
    for (int kb = 0; kb < 4; kb++)
#pragma unroll
      for (int r = 0; r < 4; r++) {
        float p = exp2f(sv[kb][r] - m_new);
        sv[kb][r] = p;
        ssum += p;
      }
    ssum += __shfl_xor(ssum, 16);
    ssum += __shfl_xor(ssum, 32);
    l_sum = l_sum * a + ssum;
    m_old = m_new;

    // broadcast alpha across layouts: O rows are q = quad*4+r
    float ar[4];
#pragma unroll
    for (int r = 0; r < 4; r++)
      ar[r] = __shfl(a, (lane & 48) + quad * 4 + r);
#pragma unroll
    for (int nb = 0; nb < 8; nb++)
#pragma unroll
      for (int r = 0; r < 4; r++) o[nb][r] *= ar[r];

    // P store: 4x ds_write_b64 of r-consecutive k into P[q=l16][k],
    // 16B-chunk swizzle c' = c ^ (l16&7)
#pragma unroll
    for (int kb = 0; kb < 4; kb++) {
      u16x4 pk;
#pragma unroll
      for (int r = 0; r < 4; r++) pk[r] = f2bf(sv[kb][r]);
      int c = kb * 2 + (quad >> 1);
      int cp = c ^ (l16 & 7);
      *(u16x4*)&pw[l16 * 64 + cp * 8 + (quad & 1) * 4] = pk;
    }

    // O += P V
#pragma unroll
    for (int kb2 = 0; kb2 < 2; kb2++) {
      int pcc = (kb2 * 4 + quad) ^ (l16 & 7);
      bf16x8 pf = *(const bf16x8*)&pw[l16 * 64 + pcc * 8];
#pragma unroll
      for (int nb = 0; nb < 8; nb++) {
        int rr = nb * 16 + l16;
        int cc = (kb2 * 4 + quad) ^ (rr & 7);
        bf16x8 vf = *(const bf16x8*)&sVc[rr * 64 + cc * 8];
        o[nb] = __builtin_amdgcn_mfma_f32_16x16x32_bf16(pf, vf, o[nb], 0, 0, 0);
      }
    }

    if (segEnd) {
      // epilogue: inv l_sum broadcast like alpha; O rows q = quad*4+r
      float linv = 1.0f / l_sum;
#pragma unroll
      for (int r = 0; r < 4; r++) {
        float ir = __shfl(linv, (lane & 48) + quad * 4 + r);
        size_t orow = (size_t)(b * T + qt * 64 + w * 16 + quad * 4 + r) * 2048 + h * HD;
#pragma unroll
        for (int nb = 0; nb < 8; nb++)
          yout[orow + nb * 16 + l16] = f2bf(o[nb][r] * ir);
      }
      if (it + 1 < total) {
        qt = qtB;
        const size_t qrow = (size_t)(b * T + qt * 64 + w * 16 + l16) * CC + h * HD;
#pragma unroll
        for (int kb = 0; kb < 4; kb++) {
          bf16x8 raw = *(const bf16x8*)&qkv[qrow + kb * 32 + quad * 8];
          bf16x8 sc;
#pragma unroll
          for (int j = 0; j < 8; j++) sc[j] = (__bf16)((float)raw[j] * qscale);
          qf[kb] = sc;
        }
        m_old = -1e30f; l_sum = 0.f;
#pragma unroll
        for (int nb = 0; nb < 8; nb++) o[nb] = (f32x4){0.f, 0.f, 0.f, 0.f};
      }
      kt = 0;
    } else {
      kt++;
    }
  }
}

// ---------------------------------------------------------------------------
extern "C" void kernel_launch(void* const* d_in, const int* in_sizes, int n_in,
                              void* d_out, int out_size, void* d_ws, size_t ws_size,
                              hipStream_t stream) {
  const float* x      = (const float*)d_in[0];   // (2,2048,2048)
  const float* W_attn = (const float*)d_in[1];   // (2048,6144)
  const float* b_attn = (const float*)d_in[2];   // (6144,)
  const float* W_proj = (const float*)d_in[3];   // (2048,2048)
  const float* b_proj = (const float*)d_in[4];   // (2048,)
  float* out = (float*)d_out;                    // (2,2048,2048) fp32

  char* ws = (char*)d_ws;
  unsigned short* x_bf  = (unsigned short*)(ws);              // 16 MiB
  unsigned short* WaT   = (unsigned short*)(ws + 16777216);   // 24 MiB
  unsigned short* WpT   = (unsigned short*)(ws + 41943040);   // 8 MiB
  unsigned short* qkv   = (unsigned short*)(ws + 50331648);   // 48 MiB
  unsigned short* vT    = (unsigned short*)(ws + 100663296);  // 16 MiB
  unsigned short* y_att = (unsigned short*)(ws + 117440512);  // 16 MiB
  // total 128 MiB

  cvt_f32_bf16_k<<<1024, 256, 0, stream>>>(x, x_bf, 8388608 / 4);
  transpose_f32_bf16<<<dim3(96, 32), 256, 0, stream>>>(W_attn, WaT, 2048, 6144);
  transpose_f32_bf16<<<dim3(32, 32), 256, 0, stream>>>(W_proj, WpT, 2048, 2048);
  // QKV: 48 n-tiles x 32 m-tiles, XCD-swizzled linear grid (6 n-tiles/XCD)
  gemm_bt<1, 6><<<dim3(1536), 256, 0, stream>>>(x_bf, WaT, b_attn, qkv, 4096, 6144, 2048);
  extract_vT_k<<<dim3(32, 2, 32), 256, 0, stream>>>(qkv, vT);
  flash_attn<<<dim3(512), 256, 0, stream>>>(qkv, vT, y_att);
  // proj: 16 n-tiles x 32 m-tiles (2 n-tiles/XCD)
  gemm_bt<0, 2><<<dim3(512), 256, 0, stream>>>(y_att, WpT, b_proj, out, 4096, 2048, 2048);
}